// Round 12
// baseline (784.871 us; speedup 1.0000x reference)
//
#include <hip/hip_runtime.h>
#include <hip/hip_bf16.h>
#include <math.h>

#define Bb 16
#define Nn 512
#define Dd 256
#define Hh 8
#define HD 32
#define Ll 3
#define INDIM 768
#define Ee 4096
#define FF 1024
#define KP 40    // gemm LDS k-pitch in shorts (32 + 8 pad)

typedef unsigned short u16;
typedef __bf16 bf16x8 __attribute__((ext_vector_type(8)));
typedef float f32x4 __attribute__((ext_vector_type(4)));
typedef u16 us8 __attribute__((ext_vector_type(8)));
typedef u16 us4 __attribute__((ext_vector_type(4)));

__device__ __forceinline__ float gelu_exact(float x) {
    return 0.5f * x * (1.0f + erff(x * 0.70710678118654752f));
}

__device__ __forceinline__ u16 f2bf(float x) {
    unsigned int u = __float_as_uint(x);
    return (u16)((u + 0x7FFFu + ((u >> 16) & 1u)) >> 16);
}
__device__ __forceinline__ float bf2f(u16 h) {
    return __uint_as_float(((unsigned int)h) << 16);
}

// ---------------- edge bucketing ----------------

__global__ __launch_bounds__(256) void zero_kernel(int* __restrict__ p, int n) {
    int gid = blockIdx.x * 256 + threadIdx.x;
    if (gid < n) p[gid] = 0;
}

__global__ __launch_bounds__(256) void count_kernel(const int* __restrict__ edge_index,
                                                    int* __restrict__ counts) {
    int gid = blockIdx.x * 256 + threadIdx.x; // B*E = 65536
    int b = gid >> 12;
    int e = gid & (Ee - 1);
    int src = edge_index[b * 2 * Ee + e];
    atomicAdd(&counts[b * Nn + src], 1);
}

__global__ __launch_bounds__(1024) void scan_kernel(const int* __restrict__ counts,
                                                    int* __restrict__ offsets,
                                                    int* __restrict__ cursor) {
    __shared__ int ssum[1024];
    int t = threadIdx.x;
    int local[8];
    int s = 0;
#pragma unroll
    for (int i = 0; i < 8; i++) { local[i] = counts[t * 8 + i]; s += local[i]; }
    ssum[t] = s;
    __syncthreads();
    for (int off = 1; off < 1024; off *= 2) {
        __syncthreads();
        int v = (t >= off) ? ssum[t - off] : 0;
        __syncthreads();
        ssum[t] += v;
    }
    __syncthreads();
    int base = (t > 0) ? ssum[t - 1] : 0;
#pragma unroll
    for (int i = 0; i < 8; i++) {
        offsets[t * 8 + i] = base;
        cursor[t * 8 + i] = base;
        base += local[i];
    }
    if (t == 1023) offsets[8192] = base;
}

__global__ __launch_bounds__(256) void scatter_kernel(const int* __restrict__ edge_index,
                                                      int* __restrict__ cursor,
                                                      int* __restrict__ elist) {
    int gid = blockIdx.x * 256 + threadIdx.x;
    int b = gid >> 12;
    int e = gid & (Ee - 1);
    int src = edge_index[b * 2 * Ee + e];
    int pos = atomicAdd(&cursor[b * Nn + src], 1);
    elist[pos] = gid;
}

// ---------------- weight split+transpose: W[K][N] fp32 -> Wh,Wl [N][K] bf16 ----------------

__global__ __launch_bounds__(256) void wsplit(const float* __restrict__ W,
                                              u16* __restrict__ Wh,
                                              u16* __restrict__ Wl,
                                              int K, int N) {
    size_t moff = (size_t)blockIdx.z * K * N;
    const float* Ws = W + moff;
    u16* Whs = Wh + moff;
    u16* Wls = Wl + moff;
    int n = blockIdx.x * 256 + threadIdx.x;
    int k0 = blockIdx.y * 8;
    float w[8];
#pragma unroll
    for (int i = 0; i < 8; i++) w[i] = Ws[(size_t)(k0 + i) * N + n];
    u16 h[8], l[8];
#pragma unroll
    for (int i = 0; i < 8; i++) {
        h[i] = f2bf(w[i]);
        l[i] = f2bf(w[i] - bf2f(h[i]));
    }
    us8 hv = {h[0], h[1], h[2], h[3], h[4], h[5], h[6], h[7]};
    us8 lv = {l[0], l[1], l[2], l[3], l[4], l[5], l[6], l[7]};
    *(us8*)&Whs[(size_t)n * K + k0] = hv;
    *(us8*)&Wls[(size_t)n * K + k0] = lv;
}

// ---------------- GEMM epilogue helper ----------------
// outmode bit0: write fp32 C; bit1: write split Ch/Cl

__device__ __forceinline__ void emit(float u, size_t idx, float* C, u16* Ch, u16* Cl, int outmode) {
    if (outmode & 1) C[idx] = u;
    if (outmode & 2) {
        u16 hh = f2bf(u);
        Ch[idx] = hh;
        Cl[idx] = f2bf(u - bf2f(hh));
    }
}

// ---------------- MFMA GEMM 64x64, fp32 A with on-the-fly split (in-proj only) --------

__global__ __launch_bounds__(256) void gemm_af64(const float* __restrict__ A,
                                                 const u16* __restrict__ Bh,
                                                 const u16* __restrict__ Bl,
                                                 const float* __restrict__ bias,
                                                 float* __restrict__ C,
                                                 u16* __restrict__ Ch,
                                                 u16* __restrict__ Cl,
                                                 int M, int K, int N, int act, int outmode) {
    __shared__ u16 sAh[64 * KP];
    __shared__ u16 sAl[64 * KP];
    __shared__ u16 sBh[64 * KP];
    __shared__ u16 sBl[64 * KP];

    int t = threadIdx.x;
    int w = t >> 6, L = t & 63;
    int wr = w >> 1, wc = w & 1;
    int lane15 = L & 15, quad = L >> 4;
    int row0 = blockIdx.y * 64, col0 = blockIdx.x * 64;

    f32x4 acc[2][2];
#pragma unroll
    for (int mi = 0; mi < 2; mi++)
#pragma unroll
        for (int ni = 0; ni < 2; ni++) acc[mi][ni] = {0.f, 0.f, 0.f, 0.f};

    int ar0 = t >> 3, akq0 = (t & 7) * 4;
    int bn0 = t >> 2, bk0 = (t & 3) * 8;

    const float* Ap0 = &A[(size_t)(row0 + ar0) * K + akq0];
    const float* Ap1 = &A[(size_t)(row0 + ar0 + 32) * K + akq0];
    const u16* Bhp = &Bh[(size_t)(col0 + bn0) * K + bk0];
    const u16* Blp = &Bl[(size_t)(col0 + bn0) * K + bk0];

    float4 av0 = *(const float4*)&Ap0[0];
    float4 av1 = *(const float4*)&Ap1[0];
    us8 bhv = *(const us8*)&Bhp[0];
    us8 blv = *(const us8*)&Blp[0];

    for (int k0 = 0; k0 < K; k0 += 32) {
        __syncthreads();
        {
            float a[4] = {av0.x, av0.y, av0.z, av0.w};
            u16 h[4], l[4];
#pragma unroll
            for (int i = 0; i < 4; i++) { h[i] = f2bf(a[i]); l[i] = f2bf(a[i] - bf2f(h[i])); }
            us4 hv = {h[0], h[1], h[2], h[3]};
            us4 lv = {l[0], l[1], l[2], l[3]};
            *(us4*)&sAh[ar0 * KP + akq0] = hv;
            *(us4*)&sAl[ar0 * KP + akq0] = lv;
        }
        {
            float a[4] = {av1.x, av1.y, av1.z, av1.w};
            u16 h[4], l[4];
#pragma unroll
            for (int i = 0; i < 4; i++) { h[i] = f2bf(a[i]); l[i] = f2bf(a[i] - bf2f(h[i])); }
            us4 hv = {h[0], h[1], h[2], h[3]};
            us4 lv = {l[0], l[1], l[2], l[3]};
            *(us4*)&sAh[(ar0 + 32) * KP + akq0] = hv;
            *(us4*)&sAl[(ar0 + 32) * KP + akq0] = lv;
        }
        *(us8*)&sBh[bn0 * KP + bk0] = bhv;
        *(us8*)&sBl[bn0 * KP + bk0] = blv;
        __syncthreads();

        if (k0 + 32 < K) {
            av0 = *(const float4*)&Ap0[k0 + 32];
            av1 = *(const float4*)&Ap1[k0 + 32];
            bhv = *(const us8*)&Bhp[k0 + 32];
            blv = *(const us8*)&Blp[k0 + 32];
        }

        us8 ahr[2], alr[2], bhr[2], blr[2];
#pragma unroll
        for (int mi = 0; mi < 2; mi++) {
            int ro = (wr * 32 + mi * 16 + lane15) * KP + quad * 8;
            ahr[mi] = *(const us8*)&sAh[ro];
            alr[mi] = *(const us8*)&sAl[ro];
        }
#pragma unroll
        for (int ni = 0; ni < 2; ni++) {
            int ro = (wc * 32 + ni * 16 + lane15) * KP + quad * 8;
            bhr[ni] = *(const us8*)&sBh[ro];
            blr[ni] = *(const us8*)&sBl[ro];
        }
#pragma unroll
        for (int mi = 0; mi < 2; mi++) {
            bf16x8 ah = *(const bf16x8*)&ahr[mi];
            bf16x8 al = *(const bf16x8*)&alr[mi];
#pragma unroll
            for (int ni = 0; ni < 2; ni++) {
                bf16x8 bh = *(const bf16x8*)&bhr[ni];
                bf16x8 bl = *(const bf16x8*)&blr[ni];
                acc[mi][ni] = __builtin_amdgcn_mfma_f32_16x16x32_bf16(ah, bh, acc[mi][ni], 0, 0, 0);
                acc[mi][ni] = __builtin_amdgcn_mfma_f32_16x16x32_bf16(ah, bl, acc[mi][ni], 0, 0, 0);
                acc[mi][ni] = __builtin_amdgcn_mfma_f32_16x16x32_bf16(al, bh, acc[mi][ni], 0, 0, 0);
            }
        }
    }

#pragma unroll
    for (int mi = 0; mi < 2; mi++) {
#pragma unroll
        for (int ni = 0; ni < 2; ni++) {
            int col = col0 + wc * 32 + ni * 16 + lane15;
            float bcol = bias[col];
#pragma unroll
            for (int r = 0; r < 4; r++) {
                int row = row0 + wr * 32 + mi * 16 + quad * 4 + r;
                float u = acc[mi][ni][r] + bcol;
                if (act == 1) u = gelu_exact(u);
                emit(u, (size_t)row * N + col, C, Ch, Cl, outmode);
            }
        }
    }
}

// ---------------- MFMA GEMM 64x64, pre-split A (Wo, FF2) ----------------

__global__ __launch_bounds__(256) void gemm_s64(const u16* __restrict__ Ah,
                                                const u16* __restrict__ Al,
                                                const u16* __restrict__ Bh,
                                                const u16* __restrict__ Bl,
                                                const float* __restrict__ bias,
                                                float* __restrict__ C,
                                                u16* __restrict__ Ch,
                                                u16* __restrict__ Cl,
                                                int M, int K, int N, int act, int outmode) {
    __shared__ u16 sAh[64 * KP];
    __shared__ u16 sAl[64 * KP];
    __shared__ u16 sBh[64 * KP];
    __shared__ u16 sBl[64 * KP];

    int t = threadIdx.x;
    int w = t >> 6, L = t & 63;
    int wr = w >> 1, wc = w & 1;
    int lane15 = L & 15, quad = L >> 4;
    int row0 = blockIdx.y * 64, col0 = blockIdx.x * 64;

    f32x4 acc[2][2];
#pragma unroll
    for (int mi = 0; mi < 2; mi++)
#pragma unroll
        for (int ni = 0; ni < 2; ni++) acc[mi][ni] = {0.f, 0.f, 0.f, 0.f};

    int r0 = t >> 2, kc = (t & 3) * 8;
    const u16* Ahp = &Ah[(size_t)(row0 + r0) * K + kc];
    const u16* Alp = &Al[(size_t)(row0 + r0) * K + kc];
    const u16* Bhp = &Bh[(size_t)(col0 + r0) * K + kc];
    const u16* Blp = &Bl[(size_t)(col0 + r0) * K + kc];

    us8 ahv = *(const us8*)&Ahp[0];
    us8 alv = *(const us8*)&Alp[0];
    us8 bhv = *(const us8*)&Bhp[0];
    us8 blv = *(const us8*)&Blp[0];

    for (int k0 = 0; k0 < K; k0 += 32) {
        __syncthreads();
        *(us8*)&sAh[r0 * KP + kc] = ahv;
        *(us8*)&sAl[r0 * KP + kc] = alv;
        *(us8*)&sBh[r0 * KP + kc] = bhv;
        *(us8*)&sBl[r0 * KP + kc] = blv;
        __syncthreads();
        if (k0 + 32 < K) {
            ahv = *(const us8*)&Ahp[k0 + 32];
            alv = *(const us8*)&Alp[k0 + 32];
            bhv = *(const us8*)&Bhp[k0 + 32];
            blv = *(const us8*)&Blp[k0 + 32];
        }
        us8 ahr[2], alr[2], bhr[2], blr[2];
#pragma unroll
        for (int mi = 0; mi < 2; mi++) {
            int ro = (wr * 32 + mi * 16 + lane15) * KP + quad * 8;
            ahr[mi] = *(const us8*)&sAh[ro];
            alr[mi] = *(const us8*)&sAl[ro];
        }
#pragma unroll
        for (int ni = 0; ni < 2; ni++) {
            int ro = (wc * 32 + ni * 16 + lane15) * KP + quad * 8;
            bhr[ni] = *(const us8*)&sBh[ro];
            blr[ni] = *(const us8*)&sBl[ro];
        }
#pragma unroll
        for (int mi = 0; mi < 2; mi++) {
            bf16x8 ah = *(const bf16x8*)&ahr[mi];
            bf16x8 al = *(const bf16x8*)&alr[mi];
#pragma unroll
            for (int ni = 0; ni < 2; ni++) {
                bf16x8 bh = *(const bf16x8*)&bhr[ni];
                bf16x8 bl = *(const bf16x8*)&blr[ni];
                acc[mi][ni] = __builtin_amdgcn_mfma_f32_16x16x32_bf16(ah, bh, acc[mi][ni], 0, 0, 0);
                acc[mi][ni] = __builtin_amdgcn_mfma_f32_16x16x32_bf16(ah, bl, acc[mi][ni], 0, 0, 0);
                acc[mi][ni] = __builtin_amdgcn_mfma_f32_16x16x32_bf16(al, bh, acc[mi][ni], 0, 0, 0);
            }
        }
    }

#pragma unroll
    for (int mi = 0; mi < 2; mi++) {
#pragma unroll
        for (int ni = 0; ni < 2; ni++) {
            int col = col0 + wc * 32 + ni * 16 + lane15;
            float bcol = bias[col];
#pragma unroll
            for (int r = 0; r < 4; r++) {
                int row = row0 + wr * 32 + mi * 16 + quad * 4 + r;
                float u = acc[mi][ni][r] + bcol;
                if (act == 1) u = gelu_exact(u);
                emit(u, (size_t)row * N + col, C, Ch, Cl, outmode);
            }
        }
    }
}

// ---------------- MFMA GEMM 128x128, pre-split A (QKV, FF1) ----------------

__global__ __launch_bounds__(256) void gemm_s128(const u16* __restrict__ Ah,
                                                 const u16* __restrict__ Al,
                                                 const u16* __restrict__ Bh,
                                                 const u16* __restrict__ Bl,
                                                 const float* __restrict__ bias,
                                                 float* __restrict__ C,
                                                 u16* __restrict__ Ch,
                                                 u16* __restrict__ Cl,
                                                 int M, int K, int N, int act, int outmode) {
    __shared__ u16 sAh[128 * KP];
    __shared__ u16 sAl[128 * KP];
    __shared__ u16 sBh[128 * KP];
    __shared__ u16 sBl[128 * KP];

    int t = threadIdx.x;
    int w = t >> 6, L = t & 63;
    int wr = w >> 1, wc = w & 1;
    int lane15 = L & 15, quad = L >> 4;
    int row0 = blockIdx.y * 128, col0 = blockIdx.x * 128;

    f32x4 acc[4][4];
#pragma unroll
    for (int mi = 0; mi < 4; mi++)
#pragma unroll
        for (int ni = 0; ni < 4; ni++) acc[mi][ni] = {0.f, 0.f, 0.f, 0.f};

    int r0 = t >> 2, kc = (t & 3) * 8;
    const u16* Ahp = &Ah[(size_t)(row0 + r0) * K + kc];
    const u16* Alp = &Al[(size_t)(row0 + r0) * K + kc];
    const u16* Bhp = &Bh[(size_t)(col0 + r0) * K + kc];
    const u16* Blp = &Bl[(size_t)(col0 + r0) * K + kc];

    us8 ahv[2], alv[2], bhv[2], blv[2];
#pragma unroll
    for (int i = 0; i < 2; i++) {
        ahv[i] = *(const us8*)&Ahp[(size_t)(64 * i) * K];
        alv[i] = *(const us8*)&Alp[(size_t)(64 * i) * K];
        bhv[i] = *(const us8*)&Bhp[(size_t)(64 * i) * K];
        blv[i] = *(const us8*)&Blp[(size_t)(64 * i) * K];
    }

    for (int k0 = 0; k0 < K; k0 += 32) {
        __syncthreads();
#pragma unroll
        for (int i = 0; i < 2; i++) {
            *(us8*)&sAh[(r0 + 64 * i) * KP + kc] = ahv[i];
            *(us8*)&sAl[(r0 + 64 * i) * KP + kc] = alv[i];
            *(us8*)&sBh[(r0 + 64 * i) * KP + kc] = bhv[i];
            *(us8*)&sBl[(r0 + 64 * i) * KP + kc] = blv[i];
        }
        __syncthreads();
        if (k0 + 32 < K) {
#pragma unroll
            for (int i = 0; i < 2; i++) {
                ahv[i] = *(const us8*)&Ahp[(size_t)(64 * i) * K + k0 + 32];
                alv[i] = *(const us8*)&Alp[(size_t)(64 * i) * K + k0 + 32];
                bhv[i] = *(const us8*)&Bhp[(size_t)(64 * i) * K + k0 + 32];
                blv[i] = *(const us8*)&Blp[(size_t)(64 * i) * K + k0 + 32];
            }
        }
        us8 ahr[4], alr[4], bhr[4], blr[4];
#pragma unroll
        for (int mi = 0; mi < 4; mi++) {
            int ro = (wr * 64 + mi * 16 + lane15) * KP + quad * 8;
            ahr[mi] = *(const us8*)&sAh[ro];
            alr[mi] = *(const us8*)&sAl[ro];
        }
#pragma unroll
        for (int ni = 0; ni < 4; ni++) {
            int ro = (wc * 64 + ni * 16 + lane15) * KP + quad * 8;
            bhr[ni] = *(const us8*)&sBh[ro];
            blr[ni] = *(const us8*)&sBl[ro];
        }
#pragma unroll
        for (int mi = 0; mi < 4; mi++) {
            bf16x8 ah = *(const bf16x8*)&ahr[mi];
            bf16x8 al = *(const bf16x8*)&alr[mi];
#pragma unroll
            for (int ni = 0; ni < 4; ni++) {
                bf16x8 bh = *(const bf16x8*)&bhr[ni];
                bf16x8 bl = *(const bf16x8*)&blr[ni];
                acc[mi][ni] = __builtin_amdgcn_mfma_f32_16x16x32_bf16(ah, bh, acc[mi][ni], 0, 0, 0);
                acc[mi][ni] = __builtin_amdgcn_mfma_f32_16x16x32_bf16(ah, bl, acc[mi][ni], 0, 0, 0);
                acc[mi][ni] = __builtin_amdgcn_mfma_f32_16x16x32_bf16(al, bh, acc[mi][ni], 0, 0, 0);
            }
        }
    }

#pragma unroll
    for (int mi = 0; mi < 4; mi++) {
#pragma unroll
        for (int ni = 0; ni < 4; ni++) {
            int col = col0 + wc * 64 + ni * 16 + lane15;
            float bcol = bias[col];
#pragma unroll
            for (int r = 0; r < 4; r++) {
                int row = row0 + wr * 64 + mi * 16 + quad * 4 + r;
                float u = acc[mi][ni][r] + bcol;
                if (act == 1) u = gelu_exact(u);
                emit(u, (size_t)row * N + col, C, Ch, Cl, outmode);
            }
        }
    }
}

// ---------------- attention v8: flash MFMA, pre-split QKV input ----------------
// qkh/qkl: split QKV [M][768]. Scale folded into fp32 S-write (bias added unscaled after).

#define SBP 132

__global__ __launch_bounds__(256, 2) void attn_kernel(const u16* __restrict__ qkh,
                                                      const u16* __restrict__ qkl,
                                                      const int* __restrict__ node_mask,
                                                      const int* __restrict__ offsets,
                                                      const int* __restrict__ elist,
                                                      const int* __restrict__ edge_index,
                                                      const int* __restrict__ edge_type,
                                                      const float* __restrict__ edge_weight,
                                                      const float* __restrict__ et_emb,
                                                      u16* __restrict__ outh,
                                                      u16* __restrict__ outl) {
    int bid = blockIdx.x;            // b*32 + h*4 + quarter
    int quarter = bid & 3;
    int h = (bid >> 2) & 7;
    int b = bid >> 5;
    int t = threadIdx.x;
    int w = t >> 6, L = t & 63;
    int quad = L >> 4, lane15 = L & 15;
    int q8 = quad * 8;

    __shared__ u16 sKh[128 * 40];
    __shared__ u16 sKl[128 * 40];
    __shared__ u16 sVh[32 * SBP];
    __shared__ u16 sVl[32 * SBP];
    __shared__ float sS[4 * 16 * SBP];

    float* Sw = &sS[w * 16 * SBP];
    const float scale = 0.17677669529663687f;
    int nbase = quarter * 128 + w * 32;
    int mt0 = t >> 5, dt = t & 31;

    us8 Qh[2], Ql[2];
#pragma unroll
    for (int sub = 0; sub < 2; sub++) {
        size_t row = (size_t)(b * Nn + nbase + sub * 16 + lane15);
        Qh[sub] = *(const us8*)&qkh[row * 768 + h * HD + q8];
        Ql[sub] = *(const us8*)&qkl[row * 768 + h * HD + q8];
    }

    float Mst[2] = {-INFINITY, -INFINITY};
    float Lst[2] = {0.0f, 0.0f};
    f32x4 O[2][2];
#pragma unroll
    for (int sub = 0; sub < 2; sub++)
#pragma unroll
        for (int dc = 0; dc < 2; dc++) O[sub][dc] = {0.f, 0.f, 0.f, 0.f};

    // prefetch tile 0 K/V (pure u16 copies — no conversion)
    u16 pkh[16], pkl[16], pvh[16], pvl[16];
#pragma unroll
    for (int j = 0; j < 16; j++) {
        size_t grow = (size_t)(b * Nn + mt0 + 8 * j) * 768 + h * HD + dt;
        pkh[j] = qkh[grow + 256];
        pkl[j] = qkl[grow + 256];
        pvh[j] = qkh[grow + 512];
        pvl[j] = qkl[grow + 512];
    }

    for (int T = 0; T < 4; T++) {
        int m0 = T * 128;
        __syncthreads();
#pragma unroll
        for (int j = 0; j < 16; j++) {
            int m = mt0 + 8 * j;
            sKh[m * 40 + dt] = pkh[j];
            sKl[m * 40 + dt] = pkl[j];
            sVh[dt * SBP + m] = pvh[j];
            sVl[dt * SBP + m] = pvl[j];
        }
        __syncthreads();
        if (T < 3) {
#pragma unroll
            for (int j = 0; j < 16; j++) {
                size_t grow = (size_t)(b * Nn + (T + 1) * 128 + mt0 + 8 * j) * 768 + h * HD + dt;
                pkh[j] = qkh[grow + 256];
                pkl[j] = qkl[grow + 256];
                pvh[j] = qkh[grow + 512];
                pvl[j] = qkl[grow + 512];
            }
        }

        float mk[4][8];
#pragma unroll
        for (int c = 0; c < 4; c++) {
            int4 u0 = *(const int4*)&node_mask[b * Nn + m0 + c * 32 + q8];
            int4 u1 = *(const int4*)&node_mask[b * Nn + m0 + c * 32 + q8 + 4];
            mk[c][0] = u0.x ? 0.f : -INFINITY;
            mk[c][1] = u0.y ? 0.f : -INFINITY;
            mk[c][2] = u0.z ? 0.f : -INFINITY;
            mk[c][3] = u0.w ? 0.f : -INFINITY;
            mk[c][4] = u1.x ? 0.f : -INFINITY;
            mk[c][5] = u1.y ? 0.f : -INFINITY;
            mk[c][6] = u1.z ? 0.f : -INFINITY;
            mk[c][7] = u1.w ? 0.f : -INFINITY;
        }

#pragma unroll
        for (int sub = 0; sub < 2; sub++) {
            int nsub = nbase + sub * 16;
            bf16x8 qh = *(const bf16x8*)&Qh[sub];
            bf16x8 ql = *(const bf16x8*)&Ql[sub];

            f32x4 accS[8];
#pragma unroll
            for (int mc = 0; mc < 8; mc++) accS[mc] = {0.f, 0.f, 0.f, 0.f};
#pragma unroll
            for (int mc = 0; mc < 8; mc++) {
                us8 khr = *(const us8*)&sKh[(mc * 16 + lane15) * 40 + q8];
                us8 klr = *(const us8*)&sKl[(mc * 16 + lane15) * 40 + q8];
                bf16x8 kh = *(const bf16x8*)&khr;
                bf16x8 kl = *(const bf16x8*)&klr;
                accS[mc] = __builtin_amdgcn_mfma_f32_16x16x32_bf16(qh, kh, accS[mc], 0, 0, 0);
                accS[mc] = __builtin_amdgcn_mfma_f32_16x16x32_bf16(qh, kl, accS[mc], 0, 0, 0);
                accS[mc] = __builtin_amdgcn_mfma_f32_16x16x32_bf16(ql, kh, accS[mc], 0, 0, 0);
            }
            // scale applied here (bias added unscaled afterwards — matches reference)
#pragma unroll
            for (int mc = 0; mc < 8; mc++)
#pragma unroll
                for (int r = 0; r < 4; r++)
                    Sw[(quad * 4 + r) * SBP + mc * 16 + lane15] = accS[mc][r] * scale;
            asm volatile("s_waitcnt lgkmcnt(0)" ::: "memory");

            int beg = offsets[b * Nn + nsub];
            int end = offsets[b * Nn + nsub + 16];
            for (int i = beg + L; i < end; i += 64) {
                int ge = elist[i];
                int e = ge & (Ee - 1);
                int dst = edge_index[b * 2 * Ee + Ee + e];
                if (dst >= m0 && dst < m0 + 128) {
                    int src = edge_index[b * 2 * Ee + e];
                    int ty = edge_type[b * Ee + e];
                    float wgt = edge_weight[b * Ee + e];
                    float val = et_emb[ty * Hh + h] + (ty == 2 ? wgt : 0.0f);
                    atomicAdd(&Sw[(src - nsub) * SBP + (dst - m0)], val);
                }
            }
            asm volatile("s_waitcnt lgkmcnt(0)" ::: "memory");

            float s[4][8];
#pragma unroll
            for (int c = 0; c < 4; c++) {
                float4 a = *(const float4*)&Sw[lane15 * SBP + c * 32 + q8];
                float4 bq = *(const float4*)&Sw[lane15 * SBP + c * 32 + q8 + 4];
                s[c][0] = a.x + mk[c][0];  s[c][1] = a.y + mk[c][1];
                s[c][2] = a.z + mk[c][2];  s[c][3] = a.w + mk[c][3];
                s[c][4] = bq.x + mk[c][4]; s[c][5] = bq.y + mk[c][5];
                s[c][6] = bq.z + mk[c][6]; s[c][7] = bq.w + mk[c][7];
            }
            float mx = s[0][0];
#pragma unroll
            for (int c = 0; c < 4; c++)
#pragma unroll
                for (int j = 0; j < 8; j++) mx = fmaxf(mx, s[c][j]);
            mx = fmaxf(mx, __shfl_xor(mx, 16));
            mx = fmaxf(mx, __shfl_xor(mx, 32));
            float Mnew = fmaxf(Mst[sub], mx);
            float alpha = __expf(Mst[sub] - Mnew);
            float rs = 0.0f;
#pragma unroll
            for (int c = 0; c < 4; c++)
#pragma unroll
                for (int j = 0; j < 8; j++) {
                    s[c][j] = __expf(s[c][j] - Mnew);
                    rs += s[c][j];
                }
            rs += __shfl_xor(rs, 16);
            rs += __shfl_xor(rs, 32);
            Lst[sub] = Lst[sub] * alpha + rs;
            Mst[sub] = Mnew;

            us8 Ph[4], Pl[4];
#pragma unroll
            for (int c = 0; c < 4; c++)
#pragma unroll
                for (int j = 0; j < 8; j++) {
                    u16 ph = f2bf(s[c][j]);
                    Ph[c][j] = ph;
                    Pl[c][j] = f2bf(s[c][j] - bf2f(ph));
                }

            float aD[4];
#pragma unroll
            for (int r = 0; r < 4; r++) aD[r] = __shfl(alpha, (L & 48) | (quad * 4 + r));
#pragma unroll
            for (int dc = 0; dc < 2; dc++)
#pragma unroll
                for (int r = 0; r < 4; r++) O[sub][dc][r] *= aD[r];

#pragma unroll
            for (int c = 0; c < 4; c++) {
                bf16x8 ph = *(const bf16x8*)&Ph[c];
                bf16x8 pl = *(const bf16x8*)&Pl[c];
#pragma unroll
                for (int dc = 0; dc < 2; dc++) {
                    us8 vhr = *(const us8*)&sVh[(dc * 16 + lane15) * SBP + c * 32 + q8];
                    us8 vlr = *(const us8*)&sVl[(dc * 16 + lane15) * SBP + c * 32 + q8];
                    bf16x8 vh = *(const bf16x8*)&vhr;
                    bf16x8 vl = *(const bf16x8*)&vlr;
                    O[sub][dc] = __builtin_amdgcn_mfma_f32_16x16x32_bf16(ph, vh, O[sub][dc], 0, 0, 0);
                    O[sub][dc] = __builtin_amdgcn_mfma_f32_16x16x32_bf16(ph, vl, O[sub][dc], 0, 0, 0);
                    O[sub][dc] = __builtin_amdgcn_mfma_f32_16x16x32_bf16(pl, vh, O[sub][dc], 0, 0, 0);
                }
            }
        }
    }

#pragma unroll
    for (int sub = 0; sub < 2; sub++) {
        float linv = 1.0f / Lst[sub];
        float lD[4];
#pragma unroll
        for (int r = 0; r < 4; r++) lD[r] = __shfl(linv, (L & 48) | (quad * 4 + r));
#pragma unroll
        for (int dc = 0; dc < 2; dc++)
#pragma unroll
            for (int r = 0; r < 4; r++) {
                int row = nbase + sub * 16 + quad * 4 + r;
                size_t idx = (size_t)(b * Nn + row) * Dd + h * HD + dc * 16 + lane15;
                float u = O[sub][dc][r] * lD[r];
                u16 hh = f2bf(u);
                outh[idx] = hh;
                outl[idx] = f2bf(u - bf2f(hh));
            }
    }
}

// ---------------- residual + LayerNorm, emits fp32 + split ----------------

__global__ __launch_bounds__(256) void ln_kernel(float* __restrict__ x,
                                                 const float* __restrict__ res,
                                                 const float* __restrict__ g,
                                                 const float* __restrict__ bta,
                                                 u16* __restrict__ xh,
                                                 u16* __restrict__ xl) {
    int row = blockIdx.x;
    int t = threadIdx.x;
    __shared__ float red[4];
    __shared__ float stats[2];
    size_t idx = (size_t)row * Dd + t;
    float v = x[idx] + res[idx];
    float sm = v;
    for (int o = 32; o > 0; o >>= 1) sm += __shfl_down(sm, o);
    if ((t & 63) == 0) red[t >> 6] = sm;
    __syncthreads();
    if (t == 0) stats[0] = (red[0] + red[1] + red[2] + red[3]) * (1.0f / Dd);
    __syncthreads();
    float mu = stats[0];
    float dv = v - mu;
    float s2 = dv * dv;
    for (int o = 32; o > 0; o >>= 1) s2 += __shfl_down(s2, o);
    if ((t & 63) == 0) red[t >> 6] = s2;
    __syncthreads();
    if (t == 0) stats[1] = 1.0f / sqrtf((red[0] + red[1] + red[2] + red[3]) * (1.0f / Dd) + 1e-5f);
    __syncthreads();
    float out = dv * stats[1] * g[t] + bta[t];
    x[idx] = out;
    u16 hh = f2bf(out);
    xh[idx] = hh;
    xl[idx] = f2bf(out - bf2f(hh));
}

// ---------------- head ----------------

__global__ __launch_bounds__(256) void pool_kernel(const float* __restrict__ x,
                                                   const int* __restrict__ text_mask,
                                                   const int* __restrict__ image_mask,
                                                   float* __restrict__ pools) {
    int b = blockIdx.y;
    int n0 = blockIdx.x * 32;
    int t = threadIdx.x;
    float tp = 0.0f, ip = 0.0f, c1 = 0.0f, c2 = 0.0f;
    for (int n = n0; n < n0 + 32; n++) {
        float xv = x[(size_t)(b * Nn + n) * Dd + t];
        int tm = text_mask[b * Nn + n];
        int im = image_mask[b * Nn + n];
        tp += tm ? xv : 0.0f;
        ip += im ? xv : 0.0f;
        c1 += (float)tm;
        c2 += (float)im;
    }
    atomicAdd(&pools[b * 514 + t], tp);
    atomicAdd(&pools[b * 514 + 256 + t], ip);
    if (t == 0) {
        atomicAdd(&pools[b * 514 + 512], c1);
        atomicAdd(&pools[b * 514 + 513], c2);
    }
}

__global__ __launch_bounds__(256) void comb_kernel(const float* __restrict__ x,
                                                   const float* __restrict__ pools,
                                                   const int* __restrict__ gidx,
                                                   float* __restrict__ comb) {
    int b = blockIdx.x;
    int t = threadIdx.x;
    __shared__ float redd[12];
    float tc = fmaxf(pools[b * 514 + 512], 1.0f);
    float ic = fmaxf(pools[b * 514 + 513], 1.0f);
    float tp = pools[b * 514 + t] / tc;
    float ip = pools[b * 514 + 256 + t] / ic;
    int gi = gidx[b];
    comb[b * 776 + t] = x[(size_t)(b * Nn + gi) * Dd + t];
    comb[b * 776 + 256 + t] = tp;
    comb[b * 776 + 512 + t] = ip;
    float dotv = tp * ip, n1v = tp * tp, n2v = ip * ip;
    for (int o = 32; o > 0; o >>= 1) {
        dotv += __shfl_down(dotv, o);
        n1v += __shfl_down(n1v, o);
        n2v += __shfl_down(n2v, o);
    }
    if ((t & 63) == 0) { redd[t >> 6] = dotv; redd[4 + (t >> 6)] = n1v; redd[8 + (t >> 6)] = n2v; }
    __syncthreads();
    if (t == 0) {
        float dd = redd[0] + redd[1] + redd[2] + redd[3];
        float a1 = fmaxf(sqrtf(redd[4] + redd[5] + redd[6] + redd[7]), 1e-6f);
        float a2 = fmaxf(sqrtf(redd[8] + redd[9] + redd[10] + redd[11]), 1e-6f);
        comb[b * 776 + 768] = 1.0f - dd / (a1 * a2);
    }
}

__global__ __launch_bounds__(256) void h1_kernel(const float* __restrict__ comb,
                                                 const float* __restrict__ Wm1,
                                                 const float* __restrict__ bm1,
                                                 float* __restrict__ h1) {
    int b = blockIdx.y;
    int jc = blockIdx.x;
    int t = threadIdx.x;
    __shared__ float scomb[776];
    __shared__ float partial[2][128];
    for (int i = t; i < 769; i += 256) scomb[i] = comb[b * 776 + i];
    __syncthreads();
    int j = jc * 128 + (t & 127);
    int kh = t >> 7;
    int kbeg = kh ? 384 : 0;
    int kend = kh ? 769 : 384;
    float acc = 0.0f;
#pragma unroll 8
    for (int k = kbeg; k < kend; k++) acc += scomb[k] * Wm1[k * 512 + j];
    partial[kh][t & 127] = acc;
    __syncthreads();
    if (t < 128) {
        float v = partial[0][t] + partial[1][t] + bm1[jc * 128 + t];
        h1[b * 512 + jc * 128 + t] = gelu_exact(v);
    }
}

__global__ __launch_bounds__(256) void head_fin(const float* __restrict__ h1,
                                                const float* __restrict__ Wm2,
                                                const float* __restrict__ bm2,
                                                const float* __restrict__ Wm3,
                                                const float* __restrict__ bm3,
                                                float* __restrict__ out) {
    int b = blockIdx.x;
    int t = threadIdx.x;
    __shared__ float h1s[512];
    __shared__ float red[4];
    for (int i = t; i < 512; i += 256) h1s[i] = h1[b * 512 + i];
    __syncthreads();
    float acc = bm2[t];
#pragma unroll 8
    for (int k = 0; k < 512; k++) acc += h1s[k] * Wm2[k * 256 + t];
    float h2 = gelu_exact(acc);
    float lv = h2 * Wm3[t];
    for (int o = 32; o > 0; o >>= 1) lv += __shfl_down(lv, o);
    if ((t & 63) == 0) red[t >> 6] = lv;
    __syncthreads();
    if (t == 0) out[b] = red[0] + red[1] + red[2] + red[3] + bm3[0];
}

// ---------------- launch ----------------

#define OFF_IN  0
#define OFF_QKV 196608
#define OFF_O   786432
#define OFF_F1  983040
#define OFF_F2  1769472
#define W_TOTAL 2555904

extern "C" void kernel_launch(void* const* d_in, const int* in_sizes, int n_in,
                              void* d_out, int out_size, void* d_ws, size_t ws_size,
                              hipStream_t stream) {
    const float* node_feats = (const float*)d_in[0];
    const int* node_mask = (const int*)d_in[1];
    const int* text_mask = (const int*)d_in[2];
    const int* image_mask = (const int*)d_in[3];
    const int* gidx = (const int*)d_in[4];
    const int* edge_index = (const int*)d_in[5];
    const int* edge_type = (const int*)d_in[6];
    const float* edge_weight = (const float*)d_in[7];
    const float* W_in = (const float*)d_in[8];
    const float* b_in = (const float*)d_in[9];
    const float* Wqkv = (const float*)d_in[10];
    const float* bqkv = (const float*)d_in[11];
    const float* Wo = (const float*)d_in[12];
    const float* bo = (const float*)d_in[13];
    const float* ln1_g = (const float*)d_in[14];
    const float* ln1_b = (const float*)d_in[15];
    const float* ln2_g = (const float*)d_in[16];
    const float* ln2_b = (const float*)d_in[17];
    const float* Wff1 = (const float*)d_in[18];
    const float* bff1 = (const float*)d_in[19];
    const float* Wff2 = (const float*)d_in[20];
    const float* bff2 = (const float*)d_in[21];
    const float* et_emb = (const float*)d_in[22];
    const float* Wm1 = (const float*)d_in[23];
    const float* bm1 = (const float*)d_in[24];
    const float* Wm2 = (const float*)d_in[25];
    const float* bm2 = (const float*)d_in[26];
    const float* Wm3 = (const float*)d_in[27];
    const float* bm3 = (const float*)d_in[28];

    const int M = Bb * Nn; // 8192
    char* ws = (char*)d_ws;
    size_t off = 0;
    auto alloc = [&](size_t bytes) {
        void* p = ws + off;
        off += (bytes + 255) & ~(size_t)255;
        return p;
    };
    float* x = (float*)alloc((size_t)M * Dd * 4);          // 8 MB
    u16* xh = (u16*)alloc((size_t)M * Dd * 2);             // 4 MB
    u16* xl = (u16*)alloc((size_t)M * Dd * 2);             // 4 MB
    u16* big = (u16*)alloc((size_t)2 * M * FF * 2);        // 32 MB union
    u16* qkh = big;                    // [M][768] (12 MB)
    u16* qkl = big + (size_t)M * 768;
    u16* ffh = big;                    // [M][1024] (16 MB) — lifetime disjoint from qk
    u16* ffl = big + (size_t)M * FF;
    u16* aoh = (u16*)alloc((size_t)M * Dd * 2);            // 4 MB
    u16* aol = (u16*)alloc((size_t)M * Dd * 2);            // 4 MB
    float* projb = (float*)alloc((size_t)M * Dd * 4);      // 8 MB
    int* counts = (int*)alloc(8192 * 4);
    int* offsets = (int*)alloc(8193 * 4);
    int* cursor = (int*)alloc(8192 * 4);
    int* elist = (int*)alloc((size_t)Bb * Ee * 4);
    float* pools = (float*)alloc((size_t)Bb * 514 * 4);
    float* comb = (float*)alloc((size_t)Bb * 776 * 4);
    float* h1 = (float*)alloc((size_t)Bb * 512 * 4);
    u16* wh = (u16*)alloc((size_t)W_TOTAL * 2);            // 5.1 MB
    u16* wl = (u16*)alloc((size_t)W_TOTAL * 2);            // 5.1 MB
    (void)ws_size;

    zero_kernel<<<32, 256, 0, stream>>>(counts, 8192);
    zero_kernel<<<(Bb * 514 + 255) / 256, 256, 0, stream>>>((int*)pools, Bb * 514);
    count_kernel<<<256, 256, 0, stream>>>(edge_index, counts);
    scan_kernel<<<1, 1024, 0, stream>>>(counts, offsets, cursor);
    scatter_kernel<<<256, 256, 0, stream>>>(edge_index, cursor, elist);

    wsplit<<<dim3(1, 96, 1), 256, 0, stream>>>(W_in, wh + OFF_IN, wl + OFF_IN, 768, 256);
    wsplit<<<dim3(3, 32, 3), 256, 0, stream>>>(Wqkv, wh + OFF_QKV, wl + OFF_QKV, 256, 768);
    wsplit<<<dim3(1, 32, 3), 256, 0, stream>>>(Wo, wh + OFF_O, wl + OFF_O, 256, 256);
    wsplit<<<dim3(4, 32, 3), 256, 0, stream>>>(Wff1, wh + OFF_F1, wl + OFF_F1, 256, 1024);
    wsplit<<<dim3(1, 128, 3), 256, 0, stream>>>(Wff2, wh + OFF_F2, wl + OFF_F2, 1024, 256);

    // input proj: fp32 A on-the-fly split; emit fp32 x + split xh/xl
    gemm_af64<<<dim3(Dd / 64, M / 64), 256, 0, stream>>>(
        node_feats, wh + OFF_IN, wl + OFF_IN, b_in, x, xh, xl, M, INDIM, Dd, 0, 3);

    for (int l = 0; l < Ll; l++) {
        // QKV: split-A, split-only output
        gemm_s128<<<dim3(768 / 128, M / 128), 256, 0, stream>>>(
            xh, xl, wh + OFF_QKV + (size_t)l * 196608, wl + OFF_QKV + (size_t)l * 196608,
            bqkv + l * 768, projb, qkh, qkl, M, Dd, 768, 0, 2);
        attn_kernel<<<Bb * Hh * 4, 256, 0, stream>>>(
            qkh, qkl, node_mask, offsets, elist, edge_index, edge_type, edge_weight, et_emb,
            aoh, aol);
        // Wo: split-A, fp32 output
        gemm_s64<<<dim3(Dd / 64, M / 64), 256, 0, stream>>>(
            aoh, aol, wh + OFF_O + (size_t)l * 65536, wl + OFF_O + (size_t)l * 65536,
            bo + l * Dd, projb, aoh, aol, M, Dd, Dd, 0, 1);
        ln_kernel<<<M, 256, 0, stream>>>(x, projb, ln1_g + l * Dd, ln1_b + l * Dd, xh, xl);
        // FF1: split-A, GELU, split-only output
        gemm_s128<<<dim3(FF / 128, M / 128), 256, 0, stream>>>(
            xh, xl, wh + OFF_F1 + (size_t)l * 262144, wl + OFF_F1 + (size_t)l * 262144,
            bff1 + l * FF, projb, ffh, ffl, M, Dd, FF, 1, 2);
        // FF2: split-A, fp32 output
        gemm_s64<<<dim3(Dd / 64, M / 64), 256, 0, stream>>>(
            ffh, ffl, wh + OFF_F2 + (size_t)l * 262144, wl + OFF_F2 + (size_t)l * 262144,
            bff2 + l * Dd, projb, aoh, aol, M, FF, Dd, 0, 1);
        ln_kernel<<<M, 256, 0, stream>>>(x, projb, ln2_g + l * Dd, ln2_b + l * Dd, xh, xl);
    }

    pool_kernel<<<dim3(16, Bb), 256, 0, stream>>>(x, text_mask, image_mask, pools);
    comb_kernel<<<Bb, 256, 0, stream>>>(x, pools, gidx, comb);
    h1_kernel<<<dim3(4, Bb), 256, 0, stream>>>(comb, Wm1, bm1, h1);
    head_fin<<<Bb, 256, 0, stream>>>(h1, Wm2, bm2, Wm3, bm3, (float*)d_out);
}

// Round 13
// 657.614 us; speedup vs baseline: 1.1935x; 1.1935x over previous
//
#include <hip/hip_runtime.h>
#include <hip/hip_bf16.h>
#include <math.h>

#define Bb 16
#define Nn 512
#define Dd 256
#define Hh 8
#define HD 32
#define Ll 3
#define INDIM 768
#define Ee 4096
#define FF 1024
#define KP 40    // gemm LDS k-pitch in shorts (32 + 8 pad)
#define NBUCK 32768  // (b)(src>>4)(dst>>7)(src&15)

typedef unsigned short u16;
typedef __bf16 bf16x8 __attribute__((ext_vector_type(8)));
typedef float f32x4 __attribute__((ext_vector_type(4)));
typedef u16 us8 __attribute__((ext_vector_type(8)));
typedef u16 us4 __attribute__((ext_vector_type(4)));

__device__ __forceinline__ float gelu_exact(float x) {
    return 0.5f * x * (1.0f + erff(x * 0.70710678118654752f));
}

__device__ __forceinline__ u16 f2bf(float x) {
    unsigned int u = __float_as_uint(x);
    return (u16)((u + 0x7FFFu + ((u >> 16) & 1u)) >> 16);
}
__device__ __forceinline__ float bf2f(u16 h) {
    return __uint_as_float(((unsigned int)h) << 16);
}

__device__ __forceinline__ int ebucket(int b, int src, int dst) {
    return ((b * 32 + (src >> 4)) * 4 + (dst >> 7)) * 16 + (src & 15);
}

// ---------------- edge bucketing ----------------

__global__ __launch_bounds__(256) void zero_kernel(int* __restrict__ p, int n) {
    int gid = blockIdx.x * 256 + threadIdx.x;
    if (gid < n) p[gid] = 0;
}

__global__ __launch_bounds__(256) void count_kernel(const int* __restrict__ edge_index,
                                                    int* __restrict__ counts) {
    int gid = blockIdx.x * 256 + threadIdx.x; // B*E = 65536
    int b = gid >> 12;
    int e = gid & (Ee - 1);
    int src = edge_index[b * 2 * Ee + e];
    int dst = edge_index[b * 2 * Ee + Ee + e];
    atomicAdd(&counts[ebucket(b, src, dst)], 1);
}

__global__ __launch_bounds__(1024) void scan_kernel(const int* __restrict__ counts,
                                                    int* __restrict__ offsets,
                                                    int* __restrict__ cursor) {
    // 1024 threads x 32 buckets = 32768
    __shared__ int ssum[1024];
    int t = threadIdx.x;
    int local[32];
    int s = 0;
#pragma unroll
    for (int i = 0; i < 32; i++) { local[i] = counts[t * 32 + i]; s += local[i]; }
    ssum[t] = s;
    __syncthreads();
    for (int off = 1; off < 1024; off *= 2) {
        __syncthreads();
        int v = (t >= off) ? ssum[t - off] : 0;
        __syncthreads();
        ssum[t] += v;
    }
    __syncthreads();
    int base = (t > 0) ? ssum[t - 1] : 0;
#pragma unroll
    for (int i = 0; i < 32; i++) {
        offsets[t * 32 + i] = base;
        cursor[t * 32 + i] = base;
        base += local[i];
    }
    if (t == 1023) offsets[NBUCK] = base;
}

__global__ __launch_bounds__(256) void scatter_kernel(const int* __restrict__ edge_index,
                                                      const int* __restrict__ edge_type,
                                                      const float* __restrict__ edge_weight,
                                                      int* __restrict__ cursor,
                                                      int2* __restrict__ pelist) {
    int gid = blockIdx.x * 256 + threadIdx.x;
    int b = gid >> 12;
    int e = gid & (Ee - 1);
    int src = edge_index[b * 2 * Ee + e];
    int dst = edge_index[b * 2 * Ee + Ee + e];
    int ty = edge_type[b * Ee + e];
    float wgt = edge_weight[b * Ee + e];
    int pos = atomicAdd(&cursor[ebucket(b, src, dst)], 1);
    int2 pe;
    pe.x = (src << 20) | (dst << 4) | ty;
    pe.y = __float_as_int(wgt);
    pelist[pos] = pe;
}

// ---------------- weight split+transpose: W[K][N] fp32 -> Wh,Wl [N][K] bf16 ----------------

__global__ __launch_bounds__(256) void wsplit(const float* __restrict__ W,
                                              u16* __restrict__ Wh,
                                              u16* __restrict__ Wl,
                                              int K, int N) {
    size_t moff = (size_t)blockIdx.z * K * N;
    const float* Ws = W + moff;
    u16* Whs = Wh + moff;
    u16* Wls = Wl + moff;
    int n = blockIdx.x * 256 + threadIdx.x;
    int k0 = blockIdx.y * 8;
    float w[8];
#pragma unroll
    for (int i = 0; i < 8; i++) w[i] = Ws[(size_t)(k0 + i) * N + n];
    u16 h[8], l[8];
#pragma unroll
    for (int i = 0; i < 8; i++) {
        h[i] = f2bf(w[i]);
        l[i] = f2bf(w[i] - bf2f(h[i]));
    }
    us8 hv = {h[0], h[1], h[2], h[3], h[4], h[5], h[6], h[7]};
    us8 lv = {l[0], l[1], l[2], l[3], l[4], l[5], l[6], l[7]};
    *(us8*)&Whs[(size_t)n * K + k0] = hv;
    *(us8*)&Wls[(size_t)n * K + k0] = lv;
}

// ---------------- MFMA GEMM 64x64 (bf16x3) — N=256 shapes ----------------

__global__ __launch_bounds__(256) void gemm_mfma64(const float* __restrict__ A,
                                                   const u16* __restrict__ Bh,
                                                   const u16* __restrict__ Bl,
                                                   const float* __restrict__ bias,
                                                   float* __restrict__ C,
                                                   int M, int K, int N, int act) {
    __shared__ u16 sAh[64 * KP];
    __shared__ u16 sAl[64 * KP];
    __shared__ u16 sBh[64 * KP];
    __shared__ u16 sBl[64 * KP];

    int t = threadIdx.x;
    int w = t >> 6, L = t & 63;
    int wr = w >> 1, wc = w & 1;
    int lane15 = L & 15, quad = L >> 4;
    int row0 = blockIdx.y * 64, col0 = blockIdx.x * 64;

    f32x4 acc[2][2];
#pragma unroll
    for (int mi = 0; mi < 2; mi++)
#pragma unroll
        for (int ni = 0; ni < 2; ni++) acc[mi][ni] = {0.f, 0.f, 0.f, 0.f};

    int ar0 = t >> 3, akq0 = (t & 7) * 4;
    int bn0 = t >> 2, bk0 = (t & 3) * 8;

    const float* Ap0 = &A[(size_t)(row0 + ar0) * K + akq0];
    const float* Ap1 = &A[(size_t)(row0 + ar0 + 32) * K + akq0];
    const u16* Bhp = &Bh[(size_t)(col0 + bn0) * K + bk0];
    const u16* Blp = &Bl[(size_t)(col0 + bn0) * K + bk0];

    float4 av0 = *(const float4*)&Ap0[0];
    float4 av1 = *(const float4*)&Ap1[0];
    us8 bhv = *(const us8*)&Bhp[0];
    us8 blv = *(const us8*)&Blp[0];

    for (int k0 = 0; k0 < K; k0 += 32) {
        __syncthreads();
        {
            float a[4] = {av0.x, av0.y, av0.z, av0.w};
            u16 h[4], l[4];
#pragma unroll
            for (int i = 0; i < 4; i++) { h[i] = f2bf(a[i]); l[i] = f2bf(a[i] - bf2f(h[i])); }
            us4 hv = {h[0], h[1], h[2], h[3]};
            us4 lv = {l[0], l[1], l[2], l[3]};
            *(us4*)&sAh[ar0 * KP + akq0] = hv;
            *(us4*)&sAl[ar0 * KP + akq0] = lv;
        }
        {
            float a[4] = {av1.x, av1.y, av1.z, av1.w};
            u16 h[4], l[4];
#pragma unroll
            for (int i = 0; i < 4; i++) { h[i] = f2bf(a[i]); l[i] = f2bf(a[i] - bf2f(h[i])); }
            us4 hv = {h[0], h[1], h[2], h[3]};
            us4 lv = {l[0], l[1], l[2], l[3]};
            *(us4*)&sAh[(ar0 + 32) * KP + akq0] = hv;
            *(us4*)&sAl[(ar0 + 32) * KP + akq0] = lv;
        }
        *(us8*)&sBh[bn0 * KP + bk0] = bhv;
        *(us8*)&sBl[bn0 * KP + bk0] = blv;
        __syncthreads();

        if (k0 + 32 < K) {
            av0 = *(const float4*)&Ap0[k0 + 32];
            av1 = *(const float4*)&Ap1[k0 + 32];
            bhv = *(const us8*)&Bhp[k0 + 32];
            blv = *(const us8*)&Blp[k0 + 32];
        }

        us8 ahr[2], alr[2], bhr[2], blr[2];
#pragma unroll
        for (int mi = 0; mi < 2; mi++) {
            int ro = (wr * 32 + mi * 16 + lane15) * KP + quad * 8;
            ahr[mi] = *(const us8*)&sAh[ro];
            alr[mi] = *(const us8*)&sAl[ro];
        }
#pragma unroll
        for (int ni = 0; ni < 2; ni++) {
            int ro = (wc * 32 + ni * 16 + lane15) * KP + quad * 8;
            bhr[ni] = *(const us8*)&sBh[ro];
            blr[ni] = *(const us8*)&sBl[ro];
        }
#pragma unroll
        for (int mi = 0; mi < 2; mi++) {
            bf16x8 ah = *(const bf16x8*)&ahr[mi];
            bf16x8 al = *(const bf16x8*)&alr[mi];
#pragma unroll
            for (int ni = 0; ni < 2; ni++) {
                bf16x8 bh = *(const bf16x8*)&bhr[ni];
                bf16x8 bl = *(const bf16x8*)&blr[ni];
                acc[mi][ni] = __builtin_amdgcn_mfma_f32_16x16x32_bf16(ah, bh, acc[mi][ni], 0, 0, 0);
                acc[mi][ni] = __builtin_amdgcn_mfma_f32_16x16x32_bf16(ah, bl, acc[mi][ni], 0, 0, 0);
                acc[mi][ni] = __builtin_amdgcn_mfma_f32_16x16x32_bf16(al, bh, acc[mi][ni], 0, 0, 0);
            }
        }
    }

#pragma unroll
    for (int mi = 0; mi < 2; mi++) {
#pragma unroll
        for (int ni = 0; ni < 2; ni++) {
            int col = col0 + wc * 32 + ni * 16 + lane15;
            float bcol = bias[col];
#pragma unroll
            for (int r = 0; r < 4; r++) {
                int row = row0 + wr * 32 + mi * 16 + quad * 4 + r;
                float u = acc[mi][ni][r] + bcol;
                if (act == 1) u = gelu_exact(u);
                C[(size_t)row * N + col] = u;
            }
        }
    }
}

// ---------------- MFMA GEMM 128x128 (bf16x3), wave tile 64x64 — N>=768 shapes -----

__global__ __launch_bounds__(256) void gemm_mfma128(const float* __restrict__ A,
                                                    const u16* __restrict__ Bh,
                                                    const u16* __restrict__ Bl,
                                                    const float* __restrict__ bias,
                                                    float* __restrict__ C,
                                                    int M, int K, int N, int act) {
    __shared__ u16 sAh[128 * KP];
    __shared__ u16 sAl[128 * KP];
    __shared__ u16 sBh[128 * KP];
    __shared__ u16 sBl[128 * KP];

    int t = threadIdx.x;
    int w = t >> 6, L = t & 63;
    int wr = w >> 1, wc = w & 1;
    int lane15 = L & 15, quad = L >> 4;
    int row0 = blockIdx.y * 128, col0 = blockIdx.x * 128;

    f32x4 acc[4][4];
#pragma unroll
    for (int mi = 0; mi < 4; mi++)
#pragma unroll
        for (int ni = 0; ni < 4; ni++) acc[mi][ni] = {0.f, 0.f, 0.f, 0.f};

    int ar0 = t >> 3, ak0 = (t & 7) * 4;
    int bn0 = t >> 2, bk0 = (t & 3) * 8;

    const float* Ap = &A[(size_t)(row0 + ar0) * K + ak0];
    const u16* Bhp = &Bh[(size_t)(col0 + bn0) * K + bk0];
    const u16* Blp = &Bl[(size_t)(col0 + bn0) * K + bk0];

    float4 av[4];
    us8 bhv[2], blv[2];
#pragma unroll
    for (int i = 0; i < 4; i++) av[i] = *(const float4*)&Ap[(size_t)(32 * i) * K];
#pragma unroll
    for (int i = 0; i < 2; i++) {
        bhv[i] = *(const us8*)&Bhp[(size_t)(64 * i) * K];
        blv[i] = *(const us8*)&Blp[(size_t)(64 * i) * K];
    }

    for (int k0 = 0; k0 < K; k0 += 32) {
        __syncthreads();
#pragma unroll
        for (int i = 0; i < 4; i++) {
            float a[4] = {av[i].x, av[i].y, av[i].z, av[i].w};
            u16 h[4], l[4];
#pragma unroll
            for (int j = 0; j < 4; j++) { h[j] = f2bf(a[j]); l[j] = f2bf(a[j] - bf2f(h[j])); }
            us4 hv = {h[0], h[1], h[2], h[3]};
            us4 lv = {l[0], l[1], l[2], l[3]};
            *(us4*)&sAh[(ar0 + 32 * i) * KP + ak0] = hv;
            *(us4*)&sAl[(ar0 + 32 * i) * KP + ak0] = lv;
        }
#pragma unroll
        for (int i = 0; i < 2; i++) {
            *(us8*)&sBh[(bn0 + 64 * i) * KP + bk0] = bhv[i];
            *(us8*)&sBl[(bn0 + 64 * i) * KP + bk0] = blv[i];
        }
        __syncthreads();

        if (k0 + 32 < K) {
#pragma unroll
            for (int i = 0; i < 4; i++) av[i] = *(const float4*)&Ap[(size_t)(32 * i) * K + k0 + 32];
#pragma unroll
            for (int i = 0; i < 2; i++) {
                bhv[i] = *(const us8*)&Bhp[(size_t)(64 * i) * K + k0 + 32];
                blv[i] = *(const us8*)&Blp[(size_t)(64 * i) * K + k0 + 32];
            }
        }

        us8 ahr[4], alr[4], bhr[4], blr[4];
#pragma unroll
        for (int mi = 0; mi < 4; mi++) {
            int ro = (wr * 64 + mi * 16 + lane15) * KP + quad * 8;
            ahr[mi] = *(const us8*)&sAh[ro];
            alr[mi] = *(const us8*)&sAl[ro];
        }
#pragma unroll
        for (int ni = 0; ni < 4; ni++) {
            int ro = (wc * 64 + ni * 16 + lane15) * KP + quad * 8;
            bhr[ni] = *(const us8*)&sBh[ro];
            blr[ni] = *(const us8*)&sBl[ro];
        }
#pragma unroll
        for (int mi = 0; mi < 4; mi++) {
            bf16x8 ah = *(const bf16x8*)&ahr[mi];
            bf16x8 al = *(const bf16x8*)&alr[mi];
#pragma unroll
            for (int ni = 0; ni < 4; ni++) {
                bf16x8 bh = *(const bf16x8*)&bhr[ni];
                bf16x8 bl = *(const bf16x8*)&blr[ni];
                acc[mi][ni] = __builtin_amdgcn_mfma_f32_16x16x32_bf16(ah, bh, acc[mi][ni], 0, 0, 0);
                acc[mi][ni] = __builtin_amdgcn_mfma_f32_16x16x32_bf16(ah, bl, acc[mi][ni], 0, 0, 0);
                acc[mi][ni] = __builtin_amdgcn_mfma_f32_16x16x32_bf16(al, bh, acc[mi][ni], 0, 0, 0);
            }
        }
    }

#pragma unroll
    for (int mi = 0; mi < 4; mi++) {
#pragma unroll
        for (int ni = 0; ni < 4; ni++) {
            int col = col0 + wc * 64 + ni * 16 + lane15;
            float bcol = bias[col];
#pragma unroll
            for (int r = 0; r < 4; r++) {
                int row = row0 + wr * 64 + mi * 16 + quad * 4 + r;
                float u = acc[mi][ni][r] + bcol;
                if (act == 1) u = gelu_exact(u);
                C[(size_t)row * N + col] = u;
            }
        }
    }
}

// ---------------- attention v9: flash MFMA + prefetch + packed exact edge buckets ------

#define SBP 132

__global__ __launch_bounds__(256, 2) void attn_kernel(const float* __restrict__ qkv,
                                                      const int* __restrict__ node_mask,
                                                      const int* __restrict__ offsets,
                                                      const int2* __restrict__ pelist,
                                                      const float* __restrict__ et_emb,
                                                      float* __restrict__ outbuf) {
    int bid = blockIdx.x;            // b*32 + h*4 + quarter
    int quarter = bid & 3;
    int h = (bid >> 2) & 7;
    int b = bid >> 5;
    int t = threadIdx.x;
    int w = t >> 6, L = t & 63;
    int quad = L >> 4, lane15 = L & 15;
    int q8 = quad * 8;

    __shared__ u16 sKh[128 * 40];
    __shared__ u16 sKl[128 * 40];
    __shared__ u16 sVh[32 * SBP];
    __shared__ u16 sVl[32 * SBP];
    __shared__ float sS[4 * 16 * SBP];

    float* Sw = &sS[w * 16 * SBP];
    const float scale = 0.17677669529663687f;
    int nbase = quarter * 128 + w * 32;
    int mt0 = t >> 5, dt = t & 31;

    // et_emb row for this head, in registers
    float etl0 = et_emb[0 * Hh + h];
    float etl1 = et_emb[1 * Hh + h];
    float etl2 = et_emb[2 * Hh + h];
    float etl3 = et_emb[3 * Hh + h];

    us8 Qh[2], Ql[2];
#pragma unroll
    for (int sub = 0; sub < 2; sub++) {
        size_t row = (size_t)(b * Nn + nbase + sub * 16 + lane15);
        float4 qa = *(const float4*)&qkv[row * 768 + h * HD + q8];
        float4 qb = *(const float4*)&qkv[row * 768 + h * HD + q8 + 4];
        float qv[8] = {qa.x, qa.y, qa.z, qa.w, qb.x, qb.y, qb.z, qb.w};
#pragma unroll
        for (int j = 0; j < 8; j++) {
            float xq = qv[j] * scale;
            u16 hh = f2bf(xq);
            Qh[sub][j] = hh;
            Ql[sub][j] = f2bf(xq - bf2f(hh));
        }
    }

    float Mst[2] = {-INFINITY, -INFINITY};
    float Lst[2] = {0.0f, 0.0f};
    f32x4 O[2][2];
#pragma unroll
    for (int sub = 0; sub < 2; sub++)
#pragma unroll
        for (int dc = 0; dc < 2; dc++) O[sub][dc] = {0.f, 0.f, 0.f, 0.f};

    float pk[16], pv[16];
#pragma unroll
    for (int j = 0; j < 16; j++) {
        size_t grow = (size_t)(b * Nn + mt0 + 8 * j) * 768 + h * HD + dt;
        pk[j] = qkv[grow + 256];
        pv[j] = qkv[grow + 512];
    }

    for (int T = 0; T < 4; T++) {
        int m0 = T * 128;
        __syncthreads();
#pragma unroll
        for (int j = 0; j < 16; j++) {
            int m = mt0 + 8 * j;
            u16 kh = f2bf(pk[j]);
            sKh[m * 40 + dt] = kh;
            sKl[m * 40 + dt] = f2bf(pk[j] - bf2f(kh));
            u16 vh = f2bf(pv[j]);
            sVh[dt * SBP + m] = vh;
            sVl[dt * SBP + m] = f2bf(pv[j] - bf2f(vh));
        }
        __syncthreads();
        if (T < 3) {
#pragma unroll
            for (int j = 0; j < 16; j++) {
                size_t grow = (size_t)(b * Nn + (T + 1) * 128 + mt0 + 8 * j) * 768 + h * HD + dt;
                pk[j] = qkv[grow + 256];
                pv[j] = qkv[grow + 512];
            }
        }

        float mk[4][8];
#pragma unroll
        for (int c = 0; c < 4; c++) {
            int4 u0 = *(const int4*)&node_mask[b * Nn + m0 + c * 32 + q8];
            int4 u1 = *(const int4*)&node_mask[b * Nn + m0 + c * 32 + q8 + 4];
            mk[c][0] = u0.x ? 0.f : -INFINITY;
            mk[c][1] = u0.y ? 0.f : -INFINITY;
            mk[c][2] = u0.z ? 0.f : -INFINITY;
            mk[c][3] = u0.w ? 0.f : -INFINITY;
            mk[c][4] = u1.x ? 0.f : -INFINITY;
            mk[c][5] = u1.y ? 0.f : -INFINITY;
            mk[c][6] = u1.z ? 0.f : -INFINITY;
            mk[c][7] = u1.w ? 0.f : -INFINITY;
        }

#pragma unroll
        for (int sub = 0; sub < 2; sub++) {
            int nsub = nbase + sub * 16;
            bf16x8 qh = *(const bf16x8*)&Qh[sub];
            bf16x8 ql = *(const bf16x8*)&Ql[sub];

            f32x4 accS[8];
#pragma unroll
            for (int mc = 0; mc < 8; mc++) accS[mc] = {0.f, 0.f, 0.f, 0.f};
#pragma unroll
            for (int mc = 0; mc < 8; mc++) {
                us8 khr = *(const us8*)&sKh[(mc * 16 + lane15) * 40 + q8];
                us8 klr = *(const us8*)&sKl[(mc * 16 + lane15) * 40 + q8];
                bf16x8 kh = *(const bf16x8*)&khr;
                bf16x8 kl = *(const bf16x8*)&klr;
                accS[mc] = __builtin_amdgcn_mfma_f32_16x16x32_bf16(qh, kh, accS[mc], 0, 0, 0);
                accS[mc] = __builtin_amdgcn_mfma_f32_16x16x32_bf16(qh, kl, accS[mc], 0, 0, 0);
                accS[mc] = __builtin_amdgcn_mfma_f32_16x16x32_bf16(ql, kh, accS[mc], 0, 0, 0);
            }
#pragma unroll
            for (int mc = 0; mc < 8; mc++)
#pragma unroll
                for (int r = 0; r < 4; r++)
                    Sw[(quad * 4 + r) * SBP + mc * 16 + lane15] = accS[mc][r];
            asm volatile("s_waitcnt lgkmcnt(0)" ::: "memory");

            // exact-bucket packed edge replay (one coalesced 8B load per edge)
            int gb = ((b * 32 + (nsub >> 4)) * 4 + T) * 16;
            int beg = offsets[gb];
            int end = offsets[gb + 16];
            for (int i = beg + L; i < end; i += 64) {
                int2 pe = pelist[i];
                int sx = pe.x >> 20;
                int dx = (pe.x >> 4) & 511;
                int ty = pe.x & 3;
                float wgt = __int_as_float(pe.y);
                float val = (ty == 0) ? etl0 : (ty == 1) ? etl1 : (ty == 2) ? etl2 : etl3;
                if (ty == 2) val += wgt;
                atomicAdd(&Sw[(sx - nsub) * SBP + (dx - m0)], val);
            }
            asm volatile("s_waitcnt lgkmcnt(0)" ::: "memory");

            float s[4][8];
#pragma unroll
            for (int c = 0; c < 4; c++) {
                float4 a = *(const float4*)&Sw[lane15 * SBP + c * 32 + q8];
                float4 bq = *(const float4*)&Sw[lane15 * SBP + c * 32 + q8 + 4];
                s[c][0] = a.x + mk[c][0];  s[c][1] = a.y + mk[c][1];
                s[c][2] = a.z + mk[c][2];  s[c][3] = a.w + mk[c][3];
                s[c][4] = bq.x + mk[c][4]; s[c][5] = bq.y + mk[c][5];
                s[c][6] = bq.z + mk[c][6]; s[c][7] = bq.w + mk[c][7];
            }
            float mx = s[0][0];
#pragma unroll
            for (int c = 0; c < 4; c++)
#pragma unroll
                for (int j = 0; j < 8; j++) mx = fmaxf(mx, s[c][j]);
            mx = fmaxf(mx, __shfl_xor(mx, 16));
            mx = fmaxf(mx, __shfl_xor(mx, 32));
            float Mnew = fmaxf(Mst[sub], mx);
            float alpha = __expf(Mst[sub] - Mnew);
            float rs = 0.0f;
#pragma unroll
            for (int c = 0; c < 4; c++)
#pragma unroll
                for (int j = 0; j < 8; j++) {
                    s[c][j] = __expf(s[c][j] - Mnew);
                    rs += s[c][j];
                }
            rs += __shfl_xor(rs, 16);
            rs += __shfl_xor(rs, 32);
            Lst[sub] = Lst[sub] * alpha + rs;
            Mst[sub] = Mnew;

            us8 Ph[4], Pl[4];
#pragma unroll
            for (int c = 0; c < 4; c++)
#pragma unroll
                for (int j = 0; j < 8; j++) {
                    u16 ph = f2bf(s[c][j]);
                    Ph[c][j] = ph;
                    Pl[c][j] = f2bf(s[c][j] - bf2f(ph));
                }

            float aD[4];
#pragma unroll
            for (int r = 0; r < 4; r++) aD[r] = __shfl(alpha, (L & 48) | (quad * 4 + r));
#pragma unroll
            for (int dc = 0; dc < 2; dc++)
#pragma unroll
                for (int r = 0; r < 4; r++) O[sub][dc][r] *= aD[r];

#pragma unroll
            for (int c = 0; c < 4; c++) {
                bf16x8 ph = *(const bf16x8*)&Ph[c];
                bf16x8 pl = *(const bf16x8*)&Pl[c];
#pragma unroll
                for (int dc = 0; dc < 2; dc++) {
                    us8 vhr = *(const us8*)&sVh[(dc * 16 + lane15) * SBP + c * 32 + q8];
                    us8 vlr = *(const us8*)&sVl[(dc * 16 + lane15) * SBP + c * 32 + q8];
                    bf16x8 vh = *(const bf16x8*)&vhr;
                    bf16x8 vl = *(const bf16x8*)&vlr;
                    O[sub][dc] = __builtin_amdgcn_mfma_f32_16x16x32_bf16(ph, vh, O[sub][dc], 0, 0, 0);
                    O[sub][dc] = __builtin_amdgcn_mfma_f32_16x16x32_bf16(ph, vl, O[sub][dc], 0, 0, 0);
                    O[sub][dc] = __builtin_amdgcn_mfma_f32_16x16x32_bf16(pl, vh, O[sub][dc], 0, 0, 0);
                }
            }
        }
    }

#pragma unroll
    for (int sub = 0; sub < 2; sub++) {
        float linv = 1.0f / Lst[sub];
        float lD[4];
#pragma unroll
        for (int r = 0; r < 4; r++) lD[r] = __shfl(linv, (L & 48) | (quad * 4 + r));
#pragma unroll
        for (int dc = 0; dc < 2; dc++)
#pragma unroll
            for (int r = 0; r < 4; r++) {
                int row = nbase + sub * 16 + quad * 4 + r;
                outbuf[(size_t)(b * Nn + row) * Dd + h * HD + dc * 16 + lane15] =
                    O[sub][dc][r] * lD[r];
            }
    }
}

// ---------------- residual + LayerNorm ----------------

__global__ __launch_bounds__(256) void ln_kernel(float* __restrict__ x,
                                                 const float* __restrict__ res,
                                                 const float* __restrict__ g,
                                                 const float* __restrict__ bta) {
    int row = blockIdx.x;
    int t = threadIdx.x;
    __shared__ float red[4];
    __shared__ float stats[2];
    size_t idx = (size_t)row * Dd + t;
    float v = x[idx] + res[idx];
    float sm = v;
    for (int o = 32; o > 0; o >>= 1) sm += __shfl_down(sm, o);
    if ((t & 63) == 0) red[t >> 6] = sm;
    __syncthreads();
    if (t == 0) stats[0] = (red[0] + red[1] + red[2] + red[3]) * (1.0f / Dd);
    __syncthreads();
    float mu = stats[0];
    float dv = v - mu;
    float s2 = dv * dv;
    for (int o = 32; o > 0; o >>= 1) s2 += __shfl_down(s2, o);
    if ((t & 63) == 0) red[t >> 6] = s2;
    __syncthreads();
    if (t == 0) stats[1] = 1.0f / sqrtf((red[0] + red[1] + red[2] + red[3]) * (1.0f / Dd) + 1e-5f);
    __syncthreads();
    x[idx] = dv * stats[1] * g[t] + bta[t];
}

// ---------------- head ----------------

__global__ __launch_bounds__(256) void pool_kernel(const float* __restrict__ x,
                                                   const int* __restrict__ text_mask,
                                                   const int* __restrict__ image_mask,
                                                   float* __restrict__ pools) {
    int b = blockIdx.y;
    int n0 = blockIdx.x * 32;
    int t = threadIdx.x;
    float tp = 0.0f, ip = 0.0f, c1 = 0.0f, c2 = 0.0f;
    for (int n = n0; n < n0 + 32; n++) {
        float xv = x[(size_t)(b * Nn + n) * Dd + t];
        int tm = text_mask[b * Nn + n];
        int im = image_mask[b * Nn + n];
        tp += tm ? xv : 0.0f;
        ip += im ? xv : 0.0f;
        c1 += (float)tm;
        c2 += (float)im;
    }
    atomicAdd(&pools[b * 514 + t], tp);
    atomicAdd(&pools[b * 514 + 256 + t], ip);
    if (t == 0) {
        atomicAdd(&pools[b * 514 + 512], c1);
        atomicAdd(&pools[b * 514 + 513], c2);
    }
}

__global__ __launch_bounds__(256) void comb_kernel(const float* __restrict__ x,
                                                   const float* __restrict__ pools,
                                                   const int* __restrict__ gidx,
                                                   float* __restrict__ comb) {
    int b = blockIdx.x;
    int t = threadIdx.x;
    __shared__ float redd[12];
    float tc = fmaxf(pools[b * 514 + 512], 1.0f);
    float ic = fmaxf(pools[b * 514 + 513], 1.0f);
    float tp = pools[b * 514 + t] / tc;
    float ip = pools[b * 514 + 256 + t] / ic;
    int gi = gidx[b];
    comb[b * 776 + t] = x[(size_t)(b * Nn + gi) * Dd + t];
    comb[b * 776 + 256 + t] = tp;
    comb[b * 776 + 512 + t] = ip;
    float dotv = tp * ip, n1v = tp * tp, n2v = ip * ip;
    for (int o = 32; o > 0; o >>= 1) {
        dotv += __shfl_down(dotv, o);
        n1v += __shfl_down(n1v, o);
        n2v += __shfl_down(n2v, o);
    }
    if ((t & 63) == 0) { redd[t >> 6] = dotv; redd[4 + (t >> 6)] = n1v; redd[8 + (t >> 6)] = n2v; }
    __syncthreads();
    if (t == 0) {
        float dd = redd[0] + redd[1] + redd[2] + redd[3];
        float a1 = fmaxf(sqrtf(redd[4] + redd[5] + redd[6] + redd[7]), 1e-6f);
        float a2 = fmaxf(sqrtf(redd[8] + redd[9] + redd[10] + redd[11]), 1e-6f);
        comb[b * 776 + 768] = 1.0f - dd / (a1 * a2);
    }
}

__global__ __launch_bounds__(256) void h1_kernel(const float* __restrict__ comb,
                                                 const float* __restrict__ Wm1,
                                                 const float* __restrict__ bm1,
                                                 float* __restrict__ h1) {
    int b = blockIdx.y;
    int jc = blockIdx.x;
    int t = threadIdx.x;
    __shared__ float scomb[776];
    __shared__ float partial[2][128];
    for (int i = t; i < 769; i += 256) scomb[i] = comb[b * 776 + i];
    __syncthreads();
    int j = jc * 128 + (t & 127);
    int kh = t >> 7;
    int kbeg = kh ? 384 : 0;
    int kend = kh ? 769 : 384;
    float acc = 0.0f;
#pragma unroll 8
    for (int k = kbeg; k < kend; k++) acc += scomb[k] * Wm1[k * 512 + j];
    partial[kh][t & 127] = acc;
    __syncthreads();
    if (t < 128) {
        float v = partial[0][t] + partial[1][t] + bm1[jc * 128 + t];
        h1[b * 512 + jc * 128 + t] = gelu_exact(v);
    }
}

__global__ __launch_bounds__(256) void head_fin(const float* __restrict__ h1,
                                                const float* __restrict__ Wm2,
                                                const float* __restrict__ bm2,
                                                const float* __restrict__ Wm3,
                                                const float* __restrict__ bm3,
                                                float* __restrict__ out) {
    int b = blockIdx.x;
    int t = threadIdx.x;
    __shared__ float h1s[512];
    __shared__ float red[4];
    for (int i = t; i < 512; i += 256) h1s[i] = h1[b * 512 + i];
    __syncthreads();
    float acc = bm2[t];
#pragma unroll 8
    for (int k = 0; k < 512; k++) acc += h1s[k] * Wm2[k * 256 + t];
    float h2 = gelu_exact(acc);
    float lv = h2 * Wm3[t];
    for (int o = 32; o > 0; o >>= 1) lv += __shfl_down(lv, o);
    if ((t & 63) == 0) red[t >> 6] = lv;
    __syncthreads();
    if (t == 0) out[b] = red[0] + red[1] + red[2] + red[3] + bm3[0];
}

// ---------------- launch ----------------

#define OFF_IN  0
#define OFF_QKV 196608
#define OFF_O   786432
#define OFF_F1  983040
#define OFF_F2  1769472
#define W_TOTAL 2555904

extern "C" void kernel_launch(void* const* d_in, const int* in_sizes, int n_in,
                              void* d_out, int out_size, void* d_ws, size_t ws_size,
                              hipStream_t stream) {
    const float* node_feats = (const float*)d_in[0];
    const int* node_mask = (const int*)d_in[1];
    const int* text_mask = (const int*)d_in[2];
    const int* image_mask = (const int*)d_in[3];
    const int* gidx = (const int*)d_in[4];
    const int* edge_index = (const int*)d_in[5];
    const int* edge_type = (const int*)d_in[6];
    const float* edge_weight = (const float*)d_in[7];
    const float* W_in = (const float*)d_in[8];
    const float* b_in = (const float*)d_in[9];
    const float* Wqkv = (const float*)d_in[10];
    const float* bqkv = (const float*)d_in[11];
    const float* Wo = (const float*)d_in[12];
    const float* bo = (const float*)d_in[13];
    const float* ln1_g = (const float*)d_in[14];
    const float* ln1_b = (const float*)d_in[15];
    const float* ln2_g = (const float*)d_in[16];
    const float* ln2_b = (const float*)d_in[17];
    const float* Wff1 = (const float*)d_in[18];
    const float* bff1 = (const float*)d_in[19];
    const float* Wff2 = (const float*)d_in[20];
    const float* bff2 = (const float*)d_in[21];
    const float* et_emb = (const float*)d_in[22];
    const float* Wm1 = (const float*)d_in[23];
    const float* bm1 = (const float*)d_in[24];
    const float* Wm2 = (const float*)d_in[25];
    const float* bm2 = (const float*)d_in[26];
    const float* Wm3 = (const float*)d_in[27];
    const float* bm3 = (const float*)d_in[28];

    const int M = Bb * Nn; // 8192
    char* ws = (char*)d_ws;
    size_t off = 0;
    auto alloc = [&](size_t bytes) {
        void* p = ws + off;
        off += (bytes + 255) & ~(size_t)255;
        return p;
    };
    float* x = (float*)alloc((size_t)M * Dd * 4);
    float* qkvb = (float*)alloc((size_t)M * FF * 4);
    float* ffb = qkvb;
    float* attnout = (float*)alloc((size_t)M * Dd * 4);
    float* projb = (float*)alloc((size_t)M * Dd * 4);
    int* counts = (int*)alloc((size_t)NBUCK * 4);
    int* offsets = (int*)alloc((size_t)(NBUCK + 1) * 4);
    int* cursor = (int*)alloc((size_t)NBUCK * 4);
    int2* pelist = (int2*)alloc((size_t)Bb * Ee * 8);
    float* pools = (float*)alloc((size_t)Bb * 514 * 4);
    float* comb = (float*)alloc((size_t)Bb * 776 * 4);
    float* h1 = (float*)alloc((size_t)Bb * 512 * 4);
    u16* wh = (u16*)alloc((size_t)W_TOTAL * 2);
    u16* wl = (u16*)alloc((size_t)W_TOTAL * 2);
    (void)ws_size;

    zero_kernel<<<NBUCK / 256, 256, 0, stream>>>(counts, NBUCK);
    zero_kernel<<<(Bb * 514 + 255) / 256, 256, 0, stream>>>((int*)pools, Bb * 514);
    count_kernel<<<256, 256, 0, stream>>>(edge_index, counts);
    scan_kernel<<<1, 1024, 0, stream>>>(counts, offsets, cursor);
    scatter_kernel<<<256, 256, 0, stream>>>(edge_index, edge_type, edge_weight, cursor, pelist);

    wsplit<<<dim3(1, 96, 1), 256, 0, stream>>>(W_in, wh + OFF_IN, wl + OFF_IN, 768, 256);
    wsplit<<<dim3(3, 32, 3), 256, 0, stream>>>(Wqkv, wh + OFF_QKV, wl + OFF_QKV, 256, 768);
    wsplit<<<dim3(1, 32, 3), 256, 0, stream>>>(Wo, wh + OFF_O, wl + OFF_O, 256, 256);
    wsplit<<<dim3(4, 32, 3), 256, 0, stream>>>(Wff1, wh + OFF_F1, wl + OFF_F1, 256, 1024);
    wsplit<<<dim3(1, 128, 3), 256, 0, stream>>>(Wff2, wh + OFF_F2, wl + OFF_F2, 1024, 256);

    gemm_mfma64<<<dim3(Dd / 64, M / 64), 256, 0, stream>>>(
        node_feats, wh + OFF_IN, wl + OFF_IN, b_in, x, M, INDIM, Dd, 0);

    for (int l = 0; l < Ll; l++) {
        gemm_mfma128<<<dim3(768 / 128, M / 128), 256, 0, stream>>>(
            x, wh + OFF_QKV + (size_t)l * 196608, wl + OFF_QKV + (size_t)l * 196608,
            bqkv + l * 768, qkvb, M, Dd, 768, 0);
        attn_kernel<<<Bb * Hh * 4, 256, 0, stream>>>(
            qkvb, node_mask, offsets, pelist, et_emb, attnout);
        gemm_mfma64<<<dim3(Dd / 64, M / 64), 256, 0, stream>>>(
            attnout, wh + OFF_O + (size_t)l * 65536, wl + OFF_O + (size_t)l * 65536,
            bo + l * Dd, projb, M, Dd, Dd, 0);
        ln_kernel<<<M, 256, 0, stream>>>(x, projb, ln1_g + l * Dd, ln1_b + l * Dd);
        gemm_mfma128<<<dim3(FF / 128, M / 128), 256, 0, stream>>>(
            x, wh + OFF_F1 + (size_t)l * 262144, wl + OFF_F1 + (size_t)l * 262144,
            bff1 + l * FF, ffb, M, Dd, FF, 1);
        gemm_mfma64<<<dim3(Dd / 64, M / 64), 256, 0, stream>>>(
            ffb, wh + OFF_F2 + (size_t)l * 262144, wl + OFF_F2 + (size_t)l * 262144,
            bff2 + l * Dd, projb, M, FF, Dd, 0);
        ln_kernel<<<M, 256, 0, stream>>>(x, projb, ln2_g + l * Dd, ln2_b + l * Dd);
    }

    pool_kernel<<<dim3(16, Bb), 256, 0, stream>>>(x, text_mask, image_mask, pools);
    comb_kernel<<<Bb, 256, 0, stream>>>(x, pools, gidx, comb);
    h1_kernel<<<dim3(4, Bb), 256, 0, stream>>>(comb, Wm1, bm1, h1);
    head_fin<<<Bb, 256, 0, stream>>>(h1, Wm2, bm2, Wm3, bm3, (float*)d_out);
}